// Round 6
// baseline (190.096 us; speedup 1.0000x reference)
//
#include <hip/hip_runtime.h>

// SparseLinearAttention: B=1, L=4096, H=16, D=64, BLKQ=BLKK=64, M=N=64, T=8.
// fp32 I/O. Pipeline: memset -> prep(K,V->bf16 swizzled tiles) -> means ->
// topk -> kvsum(MFMA+atomics) -> m2 -> fused sparse+linear attention.

#define NH   16
#define DH   64
#define NBLK 64
#define TSEL 8

typedef unsigned short u16;
typedef unsigned int   u32;
typedef __attribute__((ext_vector_type(8))) short short8;  // 8 bf16
typedef __attribute__((ext_vector_type(4))) float f4;

#define MFMA_BF16(a, b, c) __builtin_amdgcn_mfma_f32_16x16x32_bf16(a, b, c, 0, 0, 0)

__device__ __forceinline__ u16 f2bf_rne(float f) {
  u32 u = __float_as_uint(f);
  u += 0x7fffu + ((u >> 16) & 1u);
  return (u16)(u >> 16);
}
__device__ __forceinline__ u32 pk2(float a, float b) {
  return (u32)f2bf_rne(a) | ((u32)f2bf_rne(b) << 16);
}
__device__ __forceinline__ float bf2f(u16 u) { return __uint_as_float(((u32)u) << 16); }

// 8-bf16 fragment from a swizzled row-major bf16 tile (128B rows; logical
// 16B block j of row r stored at j^(r&7)). Works for LDS and global tiles.
__device__ __forceinline__ short8 frag_row(const u16* t, int row, int jblk) {
  return *(const short8*)((const char*)t + row * 128 + ((jblk ^ (row & 7)) * 16));
}

// ---------------- K0: prep — K,V -> bf16 swizzled 8KB tiles per (h,n) ------
__global__ __launch_bounds__(256) void prep_kernel(const float* __restrict__ k,
                                                   const float* __restrict__ v,
                                                   u16* __restrict__ kT,
                                                   u16* __restrict__ vT) {
  __shared__ __align__(16) char vsl[8192];
  int n = blockIdx.x, h = blockIdx.y, tid = threadIdx.x;
  // K tile: row-major bf16, swizzled; direct global->global (coalesced stores)
  char* kt_out = (char*)(kT + ((size_t)(h * 64 + n)) * 4096);
#pragma unroll
  for (int c = 0; c < 2; c++) {
    int lo = c * 4096 + tid * 16;
    int r = lo >> 7;
    int j = ((lo >> 4) & 7) ^ (r & 7);
    const float* gp = k + ((size_t)(n * 64 + r)) * 1024 + h * 64 + j * 8;
    float4 a = *(const float4*)gp;
    float4 b = *(const float4*)(gp + 4);
    *(uint4*)(kt_out + lo) = make_uint4(pk2(a.x, a.y), pk2(a.z, a.w),
                                        pk2(b.x, b.y), pk2(b.z, b.w));
  }
  // V^T tile via LDS transpose
  int key = tid & 63, e0 = (tid >> 6) * 16;
  const float* vbase = v + ((size_t)(n * 64 + key)) * 1024 + h * 64 + e0;
  int kb = key >> 3, klo = key & 7;
#pragma unroll
  for (int c4 = 0; c4 < 4; c4++) {
    float4 a = *(const float4*)(vbase + c4 * 4);
    float vv[4] = {a.x, a.y, a.z, a.w};
#pragma unroll
    for (int jj = 0; jj < 4; jj++) {
      int e = e0 + c4 * 4 + jj;
      *(u16*)(vsl + e * 128 + ((kb ^ (e & 7)) * 16) + klo * 2) = f2bf_rne(vv[jj]);
    }
  }
  __syncthreads();
  uint4* vt_out = (uint4*)(vT + ((size_t)(h * 64 + n)) * 4096);
  vt_out[tid] = ((const uint4*)vsl)[tid];
  vt_out[256 + tid] = ((const uint4*)vsl)[256 + tid];
}

// ---------------- K1: block-mean partials (row-split by 16) -----------------
__global__ __launch_bounds__(256) void means_kernel(const float* __restrict__ q,
                                                    const float* __restrict__ k,
                                                    float* __restrict__ qkp) {
  int m = blockIdx.x, rs = blockIdx.y, z = blockIdx.z;
  const float* src = z ? k : q;
  int tid = threadIdx.x;
  const float* base = src + ((size_t)(m * 64 + rs * 16)) * 1024 + tid * 4;
  float4 acc = {0.f, 0.f, 0.f, 0.f};
#pragma unroll
  for (int i = 0; i < 16; i++) {
    float4 a = *(const float4*)(base + (size_t)i * 1024);
    acc.x += a.x; acc.y += a.y; acc.z += a.z; acc.w += a.w;
  }
  *(float4*)(qkp + ((size_t)((z * 4 + rs) * 64 + m)) * 1024 + tid * 4) = acc;
}

// ---------------- K2: block scores + top-8 per (h,m) -> lut -----------------
__global__ __launch_bounds__(64) void topk_kernel(const float* __restrict__ qkp,
                                                  int* __restrict__ lut) {
  __shared__ __align__(16) float qr_s[64];
  int m = blockIdx.x, h = blockIdx.y, n = threadIdx.x;
  float qsum = 0.f;
#pragma unroll
  for (int rs = 0; rs < 4; rs++)
    qsum += qkp[((size_t)(rs * 64 + m)) * 1024 + h * 64 + n];
  qr_s[n] = qsum;
  __syncthreads();
  float s = 0.f;
#pragma unroll
  for (int rs = 0; rs < 4; rs++) {
    const float* kr = qkp + ((size_t)((4 + rs) * 64 + n)) * 1024 + h * 64;
#pragma unroll
    for (int d = 0; d < 64; d += 4) {
      float4 a = *(const float4*)(kr + d);
      float4 b = *(const float4*)(&qr_s[d]);
      s += a.x * b.x + a.y * b.y + a.z * b.z + a.w * b.w;
    }
  }
  float my = s;
  for (int t = 0; t < TSEL; t++) {
    float v = my; int idx = n;
#pragma unroll
    for (int off = 1; off < 64; off <<= 1) {
      float ov = __shfl_xor(v, off);
      int oi = __shfl_xor(idx, off);
      if (ov > v || (ov == v && oi < idx)) { v = ov; idx = oi; }
    }
    if (n == 0) lut[(h * NBLK + m) * TSEL + t] = idx;
    if (n == idx) my = -INFINITY;
  }
}

// ---------------- K3: kvsum via MFMA + device atomics -----------------------
// grid (16 bx, 16 h), 256 thr = 4 waves; wave w owns chunk n = bx*4+w.
__global__ __launch_bounds__(256) void kvsum_kernel(const float* __restrict__ k,
                                                    const u16* __restrict__ vT,
                                                    float* __restrict__ kvsum,
                                                    float* __restrict__ ksum) {
  __shared__ __align__(16) char kfs[32768];
  __shared__ float ks_red[256];
  int bx = blockIdx.x, h = blockIdx.y;
  int tid = threadIdx.x, w = tid >> 6, lane = tid & 63;
  int lq = lane & 15, quad = lane >> 4;
  char* kf_b = kfs + w * 8192;
  int n = bx * 4 + w;

  { // row softmax of K (lane = row), transposed scatter -> kfmT slab
    const float* kr = k + ((size_t)(n * 64 + lane)) * 1024 + h * 64;
    float kv[64];
#pragma unroll
    for (int c4 = 0; c4 < 16; c4++) {
      float4 a = *(const float4*)(kr + c4 * 4);
      kv[c4 * 4] = a.x; kv[c4 * 4 + 1] = a.y; kv[c4 * 4 + 2] = a.z; kv[c4 * 4 + 3] = a.w;
    }
    float mx = -INFINITY;
#pragma unroll
    for (int d = 0; d < 64; d++) mx = fmaxf(mx, kv[d]);
    float sum = 0.f;
#pragma unroll
    for (int d = 0; d < 64; d++) { kv[d] = __expf(kv[d] - mx); sum += kv[d]; }
    float inv = 1.0f / sum;
    int rb = lane >> 3, rlo = lane & 7;
#pragma unroll
    for (int d = 0; d < 64; d++) {
      *(u16*)(kf_b + d * 128 + ((rb ^ (d & 7)) * 16) + rlo * 2) = f2bf_rne(kv[d] * inv);
    }
  }
  float ksacc = 0.f;   // ksum partial: lane = d, sum kfmT row
#pragma unroll
  for (int jb = 0; jb < 8; jb++) {
    short8 x = frag_row((const u16*)kf_b, lane, jb);
#pragma unroll
    for (int e = 0; e < 8; e++) ksacc += bf2f((u16)x[e]);
  }
  ks_red[tid] = ksacc;

  const u16* vtile = vT + ((size_t)(h * 64 + n)) * 4096;
  f4 acc[4][4];
  f4 zz = {0.f, 0.f, 0.f, 0.f};
#pragma unroll
  for (int dt = 0; dt < 4; dt++)
#pragma unroll
    for (int et = 0; et < 4; et++) acc[dt][et] = zz;
#pragma unroll
  for (int ks2 = 0; ks2 < 2; ks2++) {
    short8 a_[4], b_[4];
#pragma unroll
    for (int dt = 0; dt < 4; dt++) a_[dt] = frag_row((const u16*)kf_b, dt * 16 + lq, 4 * ks2 + quad);
#pragma unroll
    for (int et = 0; et < 4; et++) b_[et] = frag_row(vtile, et * 16 + lq, 4 * ks2 + quad);
#pragma unroll
    for (int dt = 0; dt < 4; dt++)
#pragma unroll
      for (int et = 0; et < 4; et++)
        acc[dt][et] = MFMA_BF16(a_[dt], b_[et], acc[dt][et]);
  }
#pragma unroll
  for (int dt = 0; dt < 4; dt++)
#pragma unroll
    for (int et = 0; et < 4; et++)
#pragma unroll
      for (int r = 0; r < 4; r++)
        atomicAdd(&kvsum[h * 4096 + (dt * 16 + quad * 4 + r) * 64 + et * 16 + lq],
                  acc[dt][et][r]);
  __syncthreads();
  if (tid < 64)
    atomicAdd(&ksum[h * 64 + tid], ks_red[tid] + ks_red[64 + tid] +
                                   ks_red[128 + tid] + ks_red[192 + tid]);
}

// ---------------- K4: M2^T = (kvsum @ W^T)^T as swizzled bf16 tile ----------
__global__ __launch_bounds__(256) void m2_kernel(const float* __restrict__ kvsum,
                                                 const float* __restrict__ wgt,
                                                 u16* __restrict__ m2t) {
  __shared__ float kv_s[64 * 65];
  __shared__ float w_s[64 * 65];
  int h = blockIdx.x, tid = threadIdx.x;
#pragma unroll
  for (int jj = 0; jj < 16; jj++) {
    int idx = jj * 256 + tid;   // coalesced
    kv_s[(idx >> 6) * 65 + (idx & 63)] = kvsum[h * 4096 + idx];
    w_s[(idx >> 6) * 65 + (idx & 63)] = wgt[idx];
  }
  __syncthreads();
  int d = tid >> 2, e0 = (tid & 3) * 16;
  float acc[16];
#pragma unroll
  for (int e = 0; e < 16; e++) acc[e] = 0.f;
  for (int j = 0; j < 64; j++) {
    float kvj = kv_s[d * 65 + j];
#pragma unroll
    for (int e = 0; e < 16; e++)
      acc[e] = fmaf(kvj, w_s[(e0 + e) * 65 + j], acc[e]);
  }
  char* base = (char*)m2t + (size_t)h * 8192;
#pragma unroll
  for (int e = 0; e < 16; e++) {
    int ee = e0 + e;
    *(u16*)(base + ee * 128 + (((d >> 3) ^ (ee & 7)) * 16) + (d & 7) * 2) = f2bf_rne(acc[e]);
  }
}

// ---------------- K5: fused block-sparse + linear attention -----------------
// grid (64 m, 16 h), 256 thr = 4 waves. Wave w owns Q rows [w*16, w*16+16).
// Main loop reads K/V^T A-frags DIRECTLY from prepped global bf16 tiles:
// no staging, no conversions, no barriers. Linear attention fused in epilogue.
__global__ __launch_bounds__(256, 3) void fused_attn_kernel(const float* __restrict__ q,
                                                            const u16* __restrict__ kT,
                                                            const u16* __restrict__ vT,
                                                            const int* __restrict__ lut,
                                                            const u16* __restrict__ m2t,
                                                            const float* __restrict__ ksum,
                                                            const float* __restrict__ bproj,
                                                            float* __restrict__ out) {
  __shared__ __align__(16) char smem[25088];
  // [0,8K) Q | [8K,16K) P/E slabs (w*2048) | [16K,24K) m2 | 24576 ks | 24832 bias
  int m = blockIdx.x, h = blockIdx.y;
  int tid = threadIdx.x, w = tid >> 6, lane = tid & 63;
  int lq = lane & 15, quad = lane >> 4;
  u16* q_l = (u16*)smem;
  char* p_b = smem + 8192 + w * 2048;
  u16* m2_l = (u16*)(smem + 16384);
  float* ks_s = (float*)(smem + 24576);
  float* b_s = (float*)(smem + 24832);

  const int lb = (h * NBLK + m) * TSEL;
  int blks[8];
#pragma unroll
  for (int t = 0; t < 8; t++) blks[t] = lut[lb + t];

  { // stage Q (bf16 swizzled)
#pragma unroll
    for (int c = 0; c < 2; c++) {
      int lo = c * 4096 + tid * 16;
      int r = lo >> 7;
      int j = ((lo >> 4) & 7) ^ (r & 7);
      const float* gp = q + ((size_t)(m * 64 + r)) * 1024 + h * 64 + j * 8;
      float4 a = *(const float4*)gp;
      float4 b = *(const float4*)(gp + 4);
      *(uint4*)(smem + lo) = make_uint4(pk2(a.x, a.y), pk2(a.z, a.w),
                                        pk2(b.x, b.y), pk2(b.z, b.w));
    }
  }
  { // stage m2 tile + ks + bias
    const uint4* src = (const uint4*)((const char*)m2t + (size_t)h * 8192);
    ((uint4*)m2_l)[tid] = src[tid];
    ((uint4*)m2_l)[256 + tid] = src[256 + tid];
    if (tid < 64) { ks_s[tid] = ksum[h * 64 + tid]; b_s[tid] = bproj[tid]; }
  }
  __syncthreads();   // the ONLY barrier

  const int qrow = w * 16 + lq;
  short8 qf[2];
#pragma unroll
  for (int ks = 0; ks < 2; ks++) qf[ks] = frag_row(q_l, qrow, 4 * ks + quad);

  float mrun = -INFINITY, lrun = 0.f;
  f4 o[4];
  f4 zz = {0.f, 0.f, 0.f, 0.f};
#pragma unroll
  for (int et = 0; et < 4; et++) o[et] = zz;

  for (int t = 0; t < 8; t++) {
    const u16* ktile = kT + ((size_t)(h * 64 + blks[t])) * 4096;
    const u16* vtile = vT + ((size_t)(h * 64 + blks[t])) * 4096;

    // S^T = K·Q^T : A-frags straight from global K tile
    short8 af[2][4];
#pragma unroll
    for (int ks = 0; ks < 2; ks++)
#pragma unroll
      for (int kt = 0; kt < 4; kt++)
        af[ks][kt] = frag_row(ktile, kt * 16 + lq, 4 * ks + quad);
    f4 s[4];
#pragma unroll
    for (int kt = 0; kt < 4; kt++) s[kt] = zz;
#pragma unroll
    for (int ks = 0; ks < 2; ks++)
#pragma unroll
      for (int kt = 0; kt < 4; kt++)
        s[kt] = MFMA_BF16(af[ks][kt], qf[ks], s[kt]);

    // V^T A-frags (independent: overlap with softmax)
    short8 vf[2][4];
#pragma unroll
    for (int ks = 0; ks < 2; ks++)
#pragma unroll
      for (int et = 0; et < 4; et++)
        vf[ks][et] = frag_row(vtile, et * 16 + lq, 4 * ks + quad);

    // online softmax (16 scores/lane), P row lq -> wave-private slab
    float mp = -INFINITY;
#pragma unroll
    for (int kt = 0; kt < 4; kt++)
#pragma unroll
      for (int r = 0; r < 4; r++) mp = fmaxf(mp, s[kt][r]);
    mp = fmaxf(mp, __shfl_xor(mp, 16));
    mp = fmaxf(mp, __shfl_xor(mp, 32));
    mp *= 0.125f;
    float mn = fmaxf(mrun, mp);
    float al = __expf(mrun - mn);
    mrun = mn;
    float rs_ = 0.f;
#pragma unroll
    for (int kt = 0; kt < 4; kt++) {
      float p0 = __expf(fmaf(s[kt][0], 0.125f, -mn));
      float p1 = __expf(fmaf(s[kt][1], 0.125f, -mn));
      float p2 = __expf(fmaf(s[kt][2], 0.125f, -mn));
      float p3 = __expf(fmaf(s[kt][3], 0.125f, -mn));
      rs_ += p0 + p1 + p2 + p3;
      u32 lo32 = (__float_as_uint(p0) >> 16) | (__float_as_uint(p1) & 0xffff0000u);
      u32 hi32 = (__float_as_uint(p2) >> 16) | (__float_as_uint(p3) & 0xffff0000u);
      int addr = lq * 128 + (((kt * 2 + (quad >> 1)) ^ (lq & 7)) * 16) + (quad & 1) * 8;
      *(uint2*)(p_b + addr) = make_uint2(lo32, hi32);
    }
    rs_ += __shfl_xor(rs_, 16);
    rs_ += __shfl_xor(rs_, 32);
    lrun = lrun * al + rs_;
#pragma unroll
    for (int et = 0; et < 4; et++)
#pragma unroll
      for (int r = 0; r < 4; r++) o[et][r] *= al;

    // O^T += V^T · P^T
#pragma unroll
    for (int ks = 0; ks < 2; ks++) {
      short8 pf = frag_row((const u16*)p_b, lq, 4 * ks + quad);
#pragma unroll
      for (int et = 0; et < 4; et++)
        o[et] = MFMA_BF16(vf[ks][et], pf, o[et]);
    }
  }

  // ---- fused linear attention for this thread's qrow ----
  short8 qa = frag_row(q_l, qrow, 2 * quad);
  short8 qb = frag_row(q_l, qrow, 2 * quad + 1);
  float ev[16];
  float mx = -INFINITY;
#pragma unroll
  for (int j = 0; j < 8; j++) { float x = bf2f((u16)qa[j]); ev[j] = x; mx = fmaxf(mx, x); }
#pragma unroll
  for (int j = 0; j < 8; j++) { float x = bf2f((u16)qb[j]); ev[8 + j] = x; mx = fmaxf(mx, x); }
  mx = fmaxf(mx, __shfl_xor(mx, 16));
  mx = fmaxf(mx, __shfl_xor(mx, 32));
  float sum = 0.f, eks = 0.f;
#pragma unroll
  for (int j = 0; j < 16; j++) {
    float e = __expf(ev[j] - mx);
    ev[j] = e;
    sum += e;
    eks += e * ks_s[quad * 16 + j];
  }
  sum += __shfl_xor(sum, 16); sum += __shfl_xor(sum, 32);
  eks += __shfl_xor(eks, 16); eks += __shfl_xor(eks, 32);
  float invs = 1.0f / sum;
  float den = fmaf(eks, invs, 1e-6f);
  float scale = invs / den;
  // E row lq -> wave slab (blocks 2*quad, 2*quad+1)
  uint4 e0v = make_uint4(pk2(ev[0], ev[1]), pk2(ev[2], ev[3]),
                         pk2(ev[4], ev[5]), pk2(ev[6], ev[7]));
  uint4 e1v = make_uint4(pk2(ev[8], ev[9]), pk2(ev[10], ev[11]),
                         pk2(ev[12], ev[13]), pk2(ev[14], ev[15]));
  *(uint4*)(p_b + lq * 128 + (((2 * quad) ^ (lq & 7)) * 16)) = e0v;
  *(uint4*)(p_b + lq * 128 + (((2 * quad + 1) ^ (lq & 7)) * 16)) = e1v;

  f4 oc[4];
#pragma unroll
  for (int et = 0; et < 4; et++) oc[et] = zz;
#pragma unroll
  for (int ks2 = 0; ks2 < 2; ks2++) {
    short8 ef = frag_row((const u16*)p_b, lq, 4 * ks2 + quad);
#pragma unroll
    for (int et = 0; et < 4; et++)
      oc[et] = MFMA_BF16(frag_row(m2_l, et * 16 + lq, 4 * ks2 + quad), ef, oc[et]);
  }

  // ---- single write: out = o_s/l + o_l*scale + bias ----
  float invl = 1.0f / lrun;
  float* gp = out + ((size_t)(m * 64 + qrow)) * 1024 + h * 64 + quad * 4;
#pragma unroll
  for (int et = 0; et < 4; et++) {
    int e0 = et * 16 + quad * 4;
    float4 ov;
    ov.x = o[et][0] * invl + oc[et][0] * scale + b_s[e0 + 0];
    ov.y = o[et][1] * invl + oc[et][1] * scale + b_s[e0 + 1];
    ov.z = o[et][2] * invl + oc[et][2] * scale + b_s[e0 + 2];
    ov.w = o[et][3] * invl + oc[et][3] * scale + b_s[e0 + 3];
    *(float4*)(gp + et * 16) = ov;
  }
}

extern "C" void kernel_launch(void* const* d_in, const int* in_sizes, int n_in,
                              void* d_out, int out_size, void* d_ws, size_t ws_size,
                              hipStream_t stream) {
  const float* q = (const float*)d_in[0];
  const float* k = (const float*)d_in[1];
  const float* v = (const float*)d_in[2];
  const float* w = (const float*)d_in[3];
  const float* b = (const float*)d_in[4];
  float* out = (float*)d_out;

  // ws: kT 8.4MB u16 | vT 8.4MB u16 | qkp 2MB f32 | lut 32KB | kvsum 256KB |
  //     ksum 4KB | m2t 128KB u16   (total ~19.3MB)
  u16* kT = (u16*)d_ws;
  u16* vT = kT + 4194304;
  float* qkp = (float*)(vT + 4194304);
  int* lut = (int*)(qkp + 524288);
  float* kvsum = (float*)(lut + 8192);
  float* ksum = kvsum + 65536;
  u16* m2t = (u16*)(ksum + 1024);

  hipMemsetAsync(kvsum, 0, (65536 + 1024) * sizeof(float), stream);
  prep_kernel<<<dim3(64, 16), 256, 0, stream>>>(k, v, kT, vT);
  means_kernel<<<dim3(64, 4, 2), 256, 0, stream>>>(q, k, qkp);
  topk_kernel<<<dim3(64, 16), 64, 0, stream>>>(qkp, lut);
  kvsum_kernel<<<dim3(16, 16), 256, 0, stream>>>(k, vT, kvsum, ksum);
  m2_kernel<<<16, 256, 0, stream>>>(kvsum, w, m2t);
  fused_attn_kernel<<<dim3(64, 16), 256, 0, stream>>>(q, kT, vT, lut, m2t, ksum, b, out);
}

// Round 7
// 186.231 us; speedup vs baseline: 1.0208x; 1.0208x over previous
//
#include <hip/hip_runtime.h>

// SparseLinearAttention: B=1, L=4096, H=16, D=64, BLKQ=BLKK=64, M=N=64, T=8.
// fp32 I/O. Pipeline: memset -> prep(K,V->bf16 swizzled tiles) -> means ->
// topk -> kvsum(MFMA+atomics) -> m2 -> fused sparse+linear attention.
// Fused attn: LDS-staged double-buffered tiles (pure uint4 copies, tiles
// pre-converted/pre-swizzled by prep), wave-private online softmax, one
// barrier per K-block iteration, linear attention fused into the epilogue.

#define NH   16
#define DH   64
#define NBLK 64
#define TSEL 8

typedef unsigned short u16;
typedef unsigned int   u32;
typedef __attribute__((ext_vector_type(8))) short short8;  // 8 bf16
typedef __attribute__((ext_vector_type(4))) float f4;

#define MFMA_BF16(a, b, c) __builtin_amdgcn_mfma_f32_16x16x32_bf16(a, b, c, 0, 0, 0)

__device__ __forceinline__ u16 f2bf_rne(float f) {
  u32 u = __float_as_uint(f);
  u += 0x7fffu + ((u >> 16) & 1u);
  return (u16)(u >> 16);
}
__device__ __forceinline__ u32 pk2(float a, float b) {
  return (u32)f2bf_rne(a) | ((u32)f2bf_rne(b) << 16);
}
__device__ __forceinline__ float bf2f(u16 u) { return __uint_as_float(((u32)u) << 16); }

// 8-bf16 fragment from a swizzled row-major bf16 tile (128B rows; logical
// 16B block j of row r stored at j^(r&7)).
__device__ __forceinline__ short8 frag_row(const u16* t, int row, int jblk) {
  return *(const short8*)((const char*)t + row * 128 + ((jblk ^ (row & 7)) * 16));
}

// ---------------- K0: prep — K,V -> bf16 swizzled 8KB tiles per (h,n) ------
__global__ __launch_bounds__(256) void prep_kernel(const float* __restrict__ k,
                                                   const float* __restrict__ v,
                                                   u16* __restrict__ kT,
                                                   u16* __restrict__ vT) {
  __shared__ __align__(16) char vsl[8192];
  int n = blockIdx.x, h = blockIdx.y, tid = threadIdx.x;
  char* kt_out = (char*)(kT + ((size_t)(h * 64 + n)) * 4096);
#pragma unroll
  for (int c = 0; c < 2; c++) {
    int lo = c * 4096 + tid * 16;
    int r = lo >> 7;
    int j = ((lo >> 4) & 7) ^ (r & 7);
    const float* gp = k + ((size_t)(n * 64 + r)) * 1024 + h * 64 + j * 8;
    float4 a = *(const float4*)gp;
    float4 b = *(const float4*)(gp + 4);
    *(uint4*)(kt_out + lo) = make_uint4(pk2(a.x, a.y), pk2(a.z, a.w),
                                        pk2(b.x, b.y), pk2(b.z, b.w));
  }
  // V^T tile via LDS transpose
  int key = tid & 63, e0 = (tid >> 6) * 16;
  const float* vbase = v + ((size_t)(n * 64 + key)) * 1024 + h * 64 + e0;
  int kb = key >> 3, klo = key & 7;
#pragma unroll
  for (int c4 = 0; c4 < 4; c4++) {
    float4 a = *(const float4*)(vbase + c4 * 4);
    float vv[4] = {a.x, a.y, a.z, a.w};
#pragma unroll
    for (int jj = 0; jj < 4; jj++) {
      int e = e0 + c4 * 4 + jj;
      *(u16*)(vsl + e * 128 + ((kb ^ (e & 7)) * 16) + klo * 2) = f2bf_rne(vv[jj]);
    }
  }
  __syncthreads();
  uint4* vt_out = (uint4*)(vT + ((size_t)(h * 64 + n)) * 4096);
  vt_out[tid] = ((const uint4*)vsl)[tid];
  vt_out[256 + tid] = ((const uint4*)vsl)[256 + tid];
}

// ---------------- K1: block-mean partials (row-split by 16) -----------------
__global__ __launch_bounds__(256) void means_kernel(const float* __restrict__ q,
                                                    const float* __restrict__ k,
                                                    float* __restrict__ qkp) {
  int m = blockIdx.x, rs = blockIdx.y, z = blockIdx.z;
  const float* src = z ? k : q;
  int tid = threadIdx.x;
  const float* base = src + ((size_t)(m * 64 + rs * 16)) * 1024 + tid * 4;
  float4 acc = {0.f, 0.f, 0.f, 0.f};
#pragma unroll
  for (int i = 0; i < 16; i++) {
    float4 a = *(const float4*)(base + (size_t)i * 1024);
    acc.x += a.x; acc.y += a.y; acc.z += a.z; acc.w += a.w;
  }
  *(float4*)(qkp + ((size_t)((z * 4 + rs) * 64 + m)) * 1024 + tid * 4) = acc;
}

// ---------------- K2: block scores + top-8 per (h,m) -> lut -----------------
__global__ __launch_bounds__(64) void topk_kernel(const float* __restrict__ qkp,
                                                  int* __restrict__ lut) {
  __shared__ __align__(16) float qr_s[64];
  int m = blockIdx.x, h = blockIdx.y, n = threadIdx.x;
  float qsum = 0.f;
#pragma unroll
  for (int rs = 0; rs < 4; rs++)
    qsum += qkp[((size_t)(rs * 64 + m)) * 1024 + h * 64 + n];
  qr_s[n] = qsum;
  __syncthreads();
  float s = 0.f;
#pragma unroll
  for (int rs = 0; rs < 4; rs++) {
    const float* kr = qkp + ((size_t)((4 + rs) * 64 + n)) * 1024 + h * 64;
#pragma unroll
    for (int d = 0; d < 64; d += 4) {
      float4 a = *(const float4*)(kr + d);
      float4 b = *(const float4*)(&qr_s[d]);
      s += a.x * b.x + a.y * b.y + a.z * b.z + a.w * b.w;
    }
  }
  float my = s;
  for (int t = 0; t < TSEL; t++) {
    float v = my; int idx = n;
#pragma unroll
    for (int off = 1; off < 64; off <<= 1) {
      float ov = __shfl_xor(v, off);
      int oi = __shfl_xor(idx, off);
      if (ov > v || (ov == v && oi < idx)) { v = ov; idx = oi; }
    }
    if (n == 0) lut[(h * NBLK + m) * TSEL + t] = idx;
    if (n == idx) my = -INFINITY;
  }
}

// ---------------- K3: kvsum via MFMA + device atomics -----------------------
__global__ __launch_bounds__(256) void kvsum_kernel(const float* __restrict__ k,
                                                    const u16* __restrict__ vT,
                                                    float* __restrict__ kvsum,
                                                    float* __restrict__ ksum) {
  __shared__ __align__(16) char kfs[32768];
  __shared__ float ks_red[256];
  int bx = blockIdx.x, h = blockIdx.y;
  int tid = threadIdx.x, w = tid >> 6, lane = tid & 63;
  int lq = lane & 15, quad = lane >> 4;
  char* kf_b = kfs + w * 8192;
  int n = bx * 4 + w;

  { // row softmax of K (lane = row), transposed scatter -> kfmT slab
    const float* kr = k + ((size_t)(n * 64 + lane)) * 1024 + h * 64;
    float kv[64];
#pragma unroll
    for (int c4 = 0; c4 < 16; c4++) {
      float4 a = *(const float4*)(kr + c4 * 4);
      kv[c4 * 4] = a.x; kv[c4 * 4 + 1] = a.y; kv[c4 * 4 + 2] = a.z; kv[c4 * 4 + 3] = a.w;
    }
    float mx = -INFINITY;
#pragma unroll
    for (int d = 0; d < 64; d++) mx = fmaxf(mx, kv[d]);
    float sum = 0.f;
#pragma unroll
    for (int d = 0; d < 64; d++) { kv[d] = __expf(kv[d] - mx); sum += kv[d]; }
    float inv = 1.0f / sum;
    int rb = lane >> 3, rlo = lane & 7;
#pragma unroll
    for (int d = 0; d < 64; d++) {
      *(u16*)(kf_b + d * 128 + ((rb ^ (d & 7)) * 16) + rlo * 2) = f2bf_rne(kv[d] * inv);
    }
  }
  float ksacc = 0.f;   // ksum partial: lane = d, sum kfmT row
#pragma unroll
  for (int jb = 0; jb < 8; jb++) {
    short8 x = frag_row((const u16*)kf_b, lane, jb);
#pragma unroll
    for (int e = 0; e < 8; e++) ksacc += bf2f((u16)x[e]);
  }
  ks_red[tid] = ksacc;

  const u16* vtile = vT + ((size_t)(h * 64 + n)) * 4096;
  f4 acc[4][4];
  f4 zz = {0.f, 0.f, 0.f, 0.f};
#pragma unroll
  for (int dt = 0; dt < 4; dt++)
#pragma unroll
    for (int et = 0; et < 4; et++) acc[dt][et] = zz;
#pragma unroll
  for (int ks2 = 0; ks2 < 2; ks2++) {
    short8 a_[4], b_[4];
#pragma unroll
    for (int dt = 0; dt < 4; dt++) a_[dt] = frag_row((const u16*)kf_b, dt * 16 + lq, 4 * ks2 + quad);
#pragma unroll
    for (int et = 0; et < 4; et++) b_[et] = frag_row(vtile, et * 16 + lq, 4 * ks2 + quad);
#pragma unroll
    for (int dt = 0; dt < 4; dt++)
#pragma unroll
      for (int et = 0; et < 4; et++)
        acc[dt][et] = MFMA_BF16(a_[dt], b_[et], acc[dt][et]);
  }
#pragma unroll
  for (int dt = 0; dt < 4; dt++)
#pragma unroll
    for (int et = 0; et < 4; et++)
#pragma unroll
      for (int r = 0; r < 4; r++)
        atomicAdd(&kvsum[h * 4096 + (dt * 16 + quad * 4 + r) * 64 + et * 16 + lq],
                  acc[dt][et][r]);
  __syncthreads();
  if (tid < 64)
    atomicAdd(&ksum[h * 64 + tid], ks_red[tid] + ks_red[64 + tid] +
                                   ks_red[128 + tid] + ks_red[192 + tid]);
}

// ---------------- K4: M2^T = (kvsum @ W^T)^T as swizzled bf16 tile ----------
__global__ __launch_bounds__(256) void m2_kernel(const float* __restrict__ kvsum,
                                                 const float* __restrict__ wgt,
                                                 u16* __restrict__ m2t) {
  __shared__ float kv_s[64 * 65];
  __shared__ float w_s[64 * 65];
  int h = blockIdx.x, tid = threadIdx.x;
#pragma unroll
  for (int jj = 0; jj < 16; jj++) {
    int idx = jj * 256 + tid;   // coalesced
    kv_s[(idx >> 6) * 65 + (idx & 63)] = kvsum[h * 4096 + idx];
    w_s[(idx >> 6) * 65 + (idx & 63)] = wgt[idx];
  }
  __syncthreads();
  int d = tid >> 2, e0 = (tid & 3) * 16;
  float acc[16];
#pragma unroll
  for (int e = 0; e < 16; e++) acc[e] = 0.f;
  for (int j = 0; j < 64; j++) {
    float kvj = kv_s[d * 65 + j];
#pragma unroll
    for (int e = 0; e < 16; e++)
      acc[e] = fmaf(kvj, w_s[(e0 + e) * 65 + j], acc[e]);
  }
  char* base = (char*)m2t + (size_t)h * 8192;
#pragma unroll
  for (int e = 0; e < 16; e++) {
    int ee = e0 + e;
    *(u16*)(base + ee * 128 + (((d >> 3) ^ (ee & 7)) * 16) + (d & 7) * 2) = f2bf_rne(acc[e]);
  }
}

// ---------------- K5: fused block-sparse + linear attention -----------------
// grid (64 m, 16 h), 256 thr = 4 waves. Wave w owns Q rows [w*16, w*16+16).
// Prepped K/V^T tiles staged to LDS (pure uint4 copies), double-buffered with
// register prefetch of block t+1 (16 transient VGPRs); one barrier/iter.
__global__ __launch_bounds__(256, 2) void fused_attn_kernel(const float* __restrict__ q,
                                                            const u16* __restrict__ kT,
                                                            const u16* __restrict__ vT,
                                                            const int* __restrict__ lut,
                                                            const u16* __restrict__ m2t,
                                                            const float* __restrict__ ksum,
                                                            const float* __restrict__ bproj,
                                                            float* __restrict__ out) {
  __shared__ __align__(16) char smem[57856];
  // [0,8K) Q | [8K,16K) m2 | [16K,32K) buf0: K 8K + V^T 8K | [32K,48K) buf1 |
  // [48K,56K) P slabs (w*2K) | [56K,+256) ks | [+256,+512) bias
  int m = blockIdx.x, h = blockIdx.y;
  int tid = threadIdx.x, w = tid >> 6, lane = tid & 63;
  int lq = lane & 15, quad = lane >> 4;
  u16* q_l = (u16*)smem;
  u16* m2_l = (u16*)(smem + 8192);
  char* buf0 = smem + 16384;
  char* buf1 = smem + 32768;
  char* p_b = smem + 49152 + w * 2048;
  float* ks_s = (float*)(smem + 57344);
  float* b_s = (float*)(smem + 57600);

  const int lb = (h * NBLK + m) * TSEL;
  int blks[8];
#pragma unroll
  for (int t = 0; t < 8; t++) blks[t] = lut[lb + t];

  { // stage Q (bf16 swizzled; the only conversion left in this kernel)
#pragma unroll
    for (int c = 0; c < 2; c++) {
      int lo = c * 4096 + tid * 16;
      int r = lo >> 7;
      int j = ((lo >> 4) & 7) ^ (r & 7);
      const float* gp = q + ((size_t)(m * 64 + r)) * 1024 + h * 64 + j * 8;
      float4 a = *(const float4*)gp;
      float4 b = *(const float4*)(gp + 4);
      *(uint4*)(smem + lo) = make_uint4(pk2(a.x, a.y), pk2(a.z, a.w),
                                        pk2(b.x, b.y), pk2(b.z, b.w));
    }
  }
  { // stage m2 tile + ks + bias + K/V block 0 into buf0
    const uint4* src = (const uint4*)((const char*)m2t + (size_t)h * 8192);
    ((uint4*)m2_l)[tid] = src[tid];
    ((uint4*)m2_l)[256 + tid] = src[256 + tid];
    if (tid < 64) { ks_s[tid] = ksum[h * 64 + tid]; b_s[tid] = bproj[tid]; }
    const uint4* kt0 = (const uint4*)(kT + ((size_t)(h * 64 + blks[0])) * 4096);
    const uint4* vt0 = (const uint4*)(vT + ((size_t)(h * 64 + blks[0])) * 4096);
    ((uint4*)buf0)[tid] = kt0[tid];
    ((uint4*)buf0)[256 + tid] = kt0[256 + tid];
    ((uint4*)(buf0 + 8192))[tid] = vt0[tid];
    ((uint4*)(buf0 + 8192))[256 + tid] = vt0[256 + tid];
  }
  __syncthreads();

  const int qrow = w * 16 + lq;
  short8 qf[2];
#pragma unroll
  for (int ks = 0; ks < 2; ks++) qf[ks] = frag_row(q_l, qrow, 4 * ks + quad);

  float mrun = -INFINITY, lrun = 0.f;
  f4 o[4];
  f4 zz = {0.f, 0.f, 0.f, 0.f};
#pragma unroll
  for (int et = 0; et < 4; et++) o[et] = zz;

  for (int t = 0; t < 8; t++) {
    char* cb = (t & 1) ? buf1 : buf0;
    char* nb = (t & 1) ? buf0 : buf1;
    const u16* kc = (const u16*)cb;
    const u16* vc = (const u16*)(cb + 8192);

    // issue next-tile prefetch (16 transient VGPRs)
    uint4 pk0, pk1, pv0, pv1;
    if (t < 7) {
      const uint4* ktn = (const uint4*)(kT + ((size_t)(h * 64 + blks[t + 1])) * 4096);
      const uint4* vtn = (const uint4*)(vT + ((size_t)(h * 64 + blks[t + 1])) * 4096);
      pk0 = ktn[tid]; pk1 = ktn[256 + tid];
      pv0 = vtn[tid]; pv1 = vtn[256 + tid];
    }

    // S^T = K·Q^T
    f4 s[4];
#pragma unroll
    for (int kt = 0; kt < 4; kt++) s[kt] = zz;
#pragma unroll
    for (int ks = 0; ks < 2; ks++)
#pragma unroll
      for (int kt = 0; kt < 4; kt++)
        s[kt] = MFMA_BF16(frag_row(kc, kt * 16 + lq, 4 * ks + quad), qf[ks], s[kt]);

    // online softmax (16 scores/lane), P row lq -> wave-private slab
    float mp = -INFINITY;
#pragma unroll
    for (int kt = 0; kt < 4; kt++)
#pragma unroll
      for (int r = 0; r < 4; r++) mp = fmaxf(mp, s[kt][r]);
    mp = fmaxf(mp, __shfl_xor(mp, 16));
    mp = fmaxf(mp, __shfl_xor(mp, 32));
    mp *= 0.125f;
    float mn = fmaxf(mrun, mp);
    float al = __expf(mrun - mn);
    mrun = mn;
    float rs_ = 0.f;
#pragma unroll
    for (int kt = 0; kt < 4; kt++) {
      float p0 = __expf(fmaf(s[kt][0], 0.125f, -mn));
      float p1 = __expf(fmaf(s[kt][1], 0.125f, -mn));
      float p2 = __expf(fmaf(s[kt][2], 0.125f, -mn));
      float p3 = __expf(fmaf(s[kt][3], 0.125f, -mn));
      rs_ += p0 + p1 + p2 + p3;
      u32 lo32 = (__float_as_uint(p0) >> 16) | (__float_as_uint(p1) & 0xffff0000u);
      u32 hi32 = (__float_as_uint(p2) >> 16) | (__float_as_uint(p3) & 0xffff0000u);
      int addr = lq * 128 + (((kt * 2 + (quad >> 1)) ^ (lq & 7)) * 16) + (quad & 1) * 8;
      *(uint2*)(p_b + addr) = make_uint2(lo32, hi32);
    }
    rs_ += __shfl_xor(rs_, 16);
    rs_ += __shfl_xor(rs_, 32);
    lrun = lrun * al + rs_;
#pragma unroll
    for (int et = 0; et < 4; et++)
#pragma unroll
      for (int r = 0; r < 4; r++) o[et][r] *= al;

    // drain prefetch into the other buffer (no reader of nb this iteration)
    if (t < 7) {
      ((uint4*)nb)[tid] = pk0;
      ((uint4*)nb)[256 + tid] = pk1;
      ((uint4*)(nb + 8192))[tid] = pv0;
      ((uint4*)(nb + 8192))[256 + tid] = pv1;
    }

    // O^T += V^T · P^T
#pragma unroll
    for (int ks = 0; ks < 2; ks++) {
      short8 pf = frag_row((const u16*)p_b, lq, 4 * ks + quad);
#pragma unroll
      for (int et = 0; et < 4; et++)
        o[et] = MFMA_BF16(frag_row(vc, et * 16 + lq, 4 * ks + quad), pf, o[et]);
    }
    __syncthreads();
  }

  // ---- fused linear attention for this thread's qrow ----
  short8 qa = frag_row(q_l, qrow, 2 * quad);
  short8 qb = frag_row(q_l, qrow, 2 * quad + 1);
  float ev[16];
  float mx = -INFINITY;
#pragma unroll
  for (int j = 0; j < 8; j++) { float x = bf2f((u16)qa[j]); ev[j] = x; mx = fmaxf(mx, x); }
#pragma unroll
  for (int j = 0; j < 8; j++) { float x = bf2f((u16)qb[j]); ev[8 + j] = x; mx = fmaxf(mx, x); }
  mx = fmaxf(mx, __shfl_xor(mx, 16));
  mx = fmaxf(mx, __shfl_xor(mx, 32));
  float sum = 0.f, eks = 0.f;
#pragma unroll
  for (int j = 0; j < 16; j++) {
    float e = __expf(ev[j] - mx);
    ev[j] = e;
    sum += e;
    eks += e * ks_s[quad * 16 + j];
  }
  sum += __shfl_xor(sum, 16); sum += __shfl_xor(sum, 32);
  eks += __shfl_xor(eks, 16); eks += __shfl_xor(eks, 32);
  float invs = 1.0f / sum;
  float den = fmaf(eks, invs, 1e-6f);
  float scale = invs / den;
  // E row lq -> wave slab (blocks 2*quad, 2*quad+1)
  uint4 e0v = make_uint4(pk2(ev[0], ev[1]), pk2(ev[2], ev[3]),
                         pk2(ev[4], ev[5]), pk2(ev[6], ev[7]));
  uint4 e1v = make_uint4(pk2(ev[8], ev[9]), pk2(ev[10], ev[11]),
                         pk2(ev[12], ev[13]), pk2(ev[14], ev[15]));
  *(uint4*)(p_b + lq * 128 + (((2 * quad) ^ (lq & 7)) * 16)) = e0v;
  *(uint4*)(p_b + lq * 128 + (((2 * quad + 1) ^ (lq & 7)) * 16)) = e1v;

  f4 oc[4];
#pragma unroll
  for (int et = 0; et < 4; et++) oc[et] = zz;
#pragma unroll
  for (int ks2 = 0; ks2 < 2; ks2++) {
    short8 ef = frag_row((const u16*)p_b, lq, 4 * ks2 + quad);
#pragma unroll
    for (int et = 0; et < 4; et++)
      oc[et] = MFMA_BF16(frag_row(m2_l, et * 16 + lq, 4 * ks2 + quad), ef, oc[et]);
  }

  // ---- single write: out = o_s/l + o_l*scale + bias ----
  float invl = 1.0f / lrun;
  float* gp = out + ((size_t)(m * 64 + qrow)) * 1024 + h * 64 + quad * 4;
#pragma unroll
  for (int et = 0; et < 4; et++) {
    int e0 = et * 16 + quad * 4;
    float4 ov;
    ov.x = o[et][0] * invl + oc[et][0] * scale + b_s[e0 + 0];
    ov.y = o[et][1] * invl + oc[et][1] * scale + b_s[e0 + 1];
    ov.z = o[et][2] * invl + oc[et][2] * scale + b_s[e0 + 2];
    ov.w = o[et][3] * invl + oc[et][3] * scale + b_s[e0 + 3];
    *(float4*)(gp + et * 16) = ov;
  }
}

extern "C" void kernel_launch(void* const* d_in, const int* in_sizes, int n_in,
                              void* d_out, int out_size, void* d_ws, size_t ws_size,
                              hipStream_t stream) {
  const float* q = (const float*)d_in[0];
  const float* k = (const float*)d_in[1];
  const float* v = (const float*)d_in[2];
  const float* w = (const float*)d_in[3];
  const float* b = (const float*)d_in[4];
  float* out = (float*)d_out;

  // ws: kT 8.4MB u16 | vT 8.4MB u16 | qkp 2MB f32 | lut 32KB | kvsum 256KB |
  //     ksum 4KB | m2t 128KB u16
  u16* kT = (u16*)d_ws;
  u16* vT = kT + 4194304;
  float* qkp = (float*)(vT + 4194304);
  int* lut = (int*)(qkp + 524288);
  float* kvsum = (float*)(lut + 8192);
  float* ksum = kvsum + 65536;
  u16* m2t = (u16*)(ksum + 1024);

  hipMemsetAsync(kvsum, 0, (65536 + 1024) * sizeof(float), stream);
  prep_kernel<<<dim3(64, 16), 256, 0, stream>>>(k, v, kT, vT);
  means_kernel<<<dim3(64, 4, 2), 256, 0, stream>>>(q, k, qkp);
  topk_kernel<<<dim3(64, 16), 64, 0, stream>>>(qkp, lut);
  kvsum_kernel<<<dim3(16, 16), 256, 0, stream>>>(k, vT, kvsum, ksum);
  m2_kernel<<<16, 256, 0, stream>>>(kvsum, w, m2t);
  fused_attn_kernel<<<dim3(64, 16), 256, 0, stream>>>(q, kT, vT, lut, m2t, ksum, b, out);
}

// Round 8
// 155.321 us; speedup vs baseline: 1.2239x; 1.1990x over previous
//
#include <hip/hip_runtime.h>

// SparseLinearAttention: B=1, L=4096, H=16, D=64, BLKQ=BLKK=64, M=N=64, T=8.
// fp32 I/O. 4 dispatches: memset -> prep(K one-pass: kT,kfmT,kvsum,ksum,km
// [+q-means for h<4]; V->vT) -> post(topk+m2) -> fused attn (4 blk/CU).

#define NH   16
#define DH   64
#define NBLK 64
#define TSEL 8

typedef unsigned short u16;
typedef unsigned int   u32;
typedef __attribute__((ext_vector_type(8))) short short8;  // 8 bf16
typedef __attribute__((ext_vector_type(4))) float f4;

#define MFMA_BF16(a, b, c) __builtin_amdgcn_mfma_f32_16x16x32_bf16(a, b, c, 0, 0, 0)

__device__ __forceinline__ u16 f2bf_rne(float f) {
  u32 u = __float_as_uint(f);
  u += 0x7fffu + ((u >> 16) & 1u);
  return (u16)(u >> 16);
}
__device__ __forceinline__ u32 pk2(float a, float b) {
  return (u32)f2bf_rne(a) | ((u32)f2bf_rne(b) << 16);
}
__device__ __forceinline__ float bf2f(u16 u) { return __uint_as_float(((u32)u) << 16); }

// 8-bf16 fragment from a swizzled row-major bf16 tile (128B rows; logical
// 16B block j of row r stored at j^(r&7)).
__device__ __forceinline__ short8 frag_row(const u16* t, int row, int jblk) {
  return *(const short8*)((const char*)t + row * 128 + ((jblk ^ (row & 7)) * 16));
}

// ---------------- K_A: one-pass prep over K/V + kvsum + km (+ q-means) ------
// grid (64 n, 16 h), 256 thr. Thread = (row = tid&63, quarter = tid>>6):
// owns 16 contiguous cols of its row for both K and V.
__global__ __launch_bounds__(256) void prep_kernel(const float* __restrict__ q,
                                                   const float* __restrict__ k,
                                                   const float* __restrict__ v,
                                                   u16* __restrict__ kT,
                                                   u16* __restrict__ vT,
                                                   float* __restrict__ kvsum,
                                                   float* __restrict__ ksum,
                                                   float* __restrict__ kmv,
                                                   float* __restrict__ qkp) {
  __shared__ __align__(16) char vsl[8192];    // V^T bf16 swizzled
  __shared__ __align__(16) char kfm[8192];    // kfm^T bf16 swizzled
  __shared__ float redmx[256];
  __shared__ float redsm[256];
  __shared__ float ksred[256];
  int n = blockIdx.x, h = blockIdx.y, tid = threadIdx.x;
  int w = tid >> 6, lane = tid & 63;
  int row = lane, qd = w;
  int lq = lane & 15, quad = lane >> 4;

  // ---- K row segment (16 floats) ----
  float kv[16];
  {
    const float* kr = k + (size_t)(n * 64 + row) * 1024 + h * 64 + qd * 16;
#pragma unroll
    for (int c4 = 0; c4 < 4; c4++) {
      float4 a = *(const float4*)(kr + c4 * 4);
      kv[c4 * 4] = a.x; kv[c4 * 4 + 1] = a.y; kv[c4 * 4 + 2] = a.z; kv[c4 * 4 + 3] = a.w;
    }
  }
  // ---- kT global write (raw bf16, swizzled row layout) ----
  {
    char* ktb = (char*)(kT + ((size_t)(h * 64 + n)) * 4096);
    uint4 w0 = make_uint4(pk2(kv[0], kv[1]), pk2(kv[2], kv[3]),
                          pk2(kv[4], kv[5]), pk2(kv[6], kv[7]));
    uint4 w1 = make_uint4(pk2(kv[8], kv[9]), pk2(kv[10], kv[11]),
                          pk2(kv[12], kv[13]), pk2(kv[14], kv[15]));
    *(uint4*)(ktb + row * 128 + (((2 * qd) ^ (row & 7)) * 16)) = w0;
    *(uint4*)(ktb + row * 128 + (((2 * qd + 1) ^ (row & 7)) * 16)) = w1;
  }
  // ---- V^T into LDS (scalar transpose scatter) ----
  {
    const float* vr = v + (size_t)(n * 64 + row) * 1024 + h * 64 + qd * 16;
    int kb = row >> 3, klo = row & 7;
#pragma unroll
    for (int c4 = 0; c4 < 4; c4++) {
      float4 a = *(const float4*)(vr + c4 * 4);
      float vv[4] = {a.x, a.y, a.z, a.w};
#pragma unroll
      for (int jj = 0; jj < 4; jj++) {
        int e = qd * 16 + c4 * 4 + jj;
        *(u16*)(vsl + e * 128 + ((kb ^ (e & 7)) * 16) + klo * 2) = f2bf_rne(vv[jj]);
      }
    }
  }
  // ---- km: raw column means (wave w owns cols qd*16..+16), butterflies ----
  {
    float kmval = 0.f;
#pragma unroll
    for (int j = 0; j < 16; j++) {
      float s = kv[j];
#pragma unroll
      for (int off = 1; off < 64; off <<= 1) s += __shfl_xor(s, off);
      if (lane == j) kmval = s;
    }
    if (lane < 16) kmv[h * 4096 + n * 64 + qd * 16 + lane] = kmval * (1.0f / 64.0f);
  }
  // ---- row softmax across 4 quarters (2 LDS reduce rounds) ----
  {
    float mx = kv[0];
#pragma unroll
    for (int j = 1; j < 16; j++) mx = fmaxf(mx, kv[j]);
    redmx[qd * 64 + row] = mx;
  }
  __syncthreads();
  {
    float mx = fmaxf(fmaxf(redmx[row], redmx[64 + row]),
                     fmaxf(redmx[128 + row], redmx[192 + row]));
    float sm = 0.f;
#pragma unroll
    for (int j = 0; j < 16; j++) { kv[j] = __expf(kv[j] - mx); sm += kv[j]; }
    redsm[qd * 64 + row] = sm;
  }
  __syncthreads();
  {
    float sm = redsm[row] + redsm[64 + row] + redsm[128 + row] + redsm[192 + row];
    float inv = 1.0f / sm;
    int rb = row >> 3, rlo = row & 7;
#pragma unroll
    for (int j = 0; j < 16; j++) {
      int d = qd * 16 + j;
      *(u16*)(kfm + d * 128 + (((rb) ^ (d & 7)) * 16) + rlo * 2) = f2bf_rne(kv[j] * inv);
    }
  }
  __syncthreads();   // kfm + vsl complete

  // ---- vT global copy ----
  {
    uint4* vt_out = (uint4*)(vT + ((size_t)(h * 64 + n)) * 4096);
    vt_out[tid] = ((const uint4*)vsl)[tid];
    vt_out[256 + tid] = ((const uint4*)vsl)[256 + tid];
  }
  // ---- ksum partial: wave w sums key-blocks jb=2w,2w+1 over d=lane ----
  {
    float ks = 0.f;
    short8 x0 = frag_row((const u16*)kfm, lane, 2 * w);
    short8 x1 = frag_row((const u16*)kfm, lane, 2 * w + 1);
#pragma unroll
    for (int e = 0; e < 8; e++) ks += bf2f((u16)x0[e]) + bf2f((u16)x1[e]);
    ksred[tid] = ks;
  }
  // ---- kvsum MFMA: wave w owns d-tile dt=w ----
  {
    f4 acc[4];
    f4 zz = {0.f, 0.f, 0.f, 0.f};
#pragma unroll
    for (int et = 0; et < 4; et++) acc[et] = zz;
#pragma unroll
    for (int ks2 = 0; ks2 < 2; ks2++) {
      short8 a_ = frag_row((const u16*)kfm, w * 16 + lq, 4 * ks2 + quad);
#pragma unroll
      for (int et = 0; et < 4; et++)
        acc[et] = MFMA_BF16(a_, frag_row((const u16*)vsl, et * 16 + lq, 4 * ks2 + quad), acc[et]);
    }
#pragma unroll
    for (int et = 0; et < 4; et++)
#pragma unroll
      for (int r = 0; r < 4; r++)
        atomicAdd(&kvsum[h * 4096 + (w * 16 + quad * 4 + r) * 64 + et * 16 + lq],
                  acc[et][r]);
  }
  __syncthreads();
  if (tid < 64)
    atomicAdd(&ksum[h * 64 + tid], ksred[tid] + ksred[64 + tid] +
                                   ksred[128 + tid] + ksred[192 + tid]);

  // ---- q-mean partials folded into blocks h<4 (rs=h) ----
  if (h < 4) {
    const float* base = q + ((size_t)(n * 64 + h * 16)) * 1024 + tid * 4;
    float4 acc = {0.f, 0.f, 0.f, 0.f};
#pragma unroll
    for (int i = 0; i < 16; i++) {
      float4 a = *(const float4*)(base + (size_t)i * 1024);
      acc.x += a.x; acc.y += a.y; acc.z += a.z; acc.w += a.w;
    }
    *(float4*)(qkp + ((size_t)(h * 64 + n)) * 1024 + tid * 4) = acc;
  }
}

// ---------------- K_B: post — topk (blocks 0..255) + m2 (blocks 256..271) ---
__global__ __launch_bounds__(256) void post_kernel(const float* __restrict__ qkp,
                                                   const float* __restrict__ kmv,
                                                   const float* __restrict__ kvsum,
                                                   const float* __restrict__ wgt,
                                                   int* __restrict__ lut,
                                                   u16* __restrict__ m2t) {
  __shared__ float kv_s[64 * 65];
  __shared__ float w_s[64 * 65];
  __shared__ __align__(16) float qr_s[4][80];
  int bx = blockIdx.x, tid = threadIdx.x;
  if (bx < 256) {
    // ---- topk: h = bx>>4, wave w handles m = (bx&15)*4 + w ----
    int h = bx >> 4, w = tid >> 6, n = tid & 63;
    int m = (bx & 15) * 4 + w;
    float qsum = 0.f;
#pragma unroll
    for (int rs = 0; rs < 4; rs++)
      qsum += qkp[((size_t)(rs * 64 + m)) * 1024 + h * 64 + n];
    qr_s[w][n] = qsum;
    __syncthreads();
    const float* kr = kmv + h * 4096 + n * 64;
    float s = 0.f;
#pragma unroll
    for (int d = 0; d < 64; d += 4) {
      float4 a = *(const float4*)(kr + d);
      float4 b = *(const float4*)(&qr_s[w][d]);
      s += a.x * b.x + a.y * b.y + a.z * b.z + a.w * b.w;
    }
    float my = s;
    for (int t = 0; t < TSEL; t++) {
      float v = my; int idx = n;
#pragma unroll
      for (int off = 1; off < 64; off <<= 1) {
        float ov = __shfl_xor(v, off);
        int oi = __shfl_xor(idx, off);
        if (ov > v || (ov == v && oi < idx)) { v = ov; idx = oi; }
      }
      if (n == 0) lut[(h * NBLK + m) * TSEL + t] = idx;
      if (n == idx) my = -INFINITY;
    }
  } else {
    // ---- m2 for h = bx - 256 ----
    int h = bx - 256;
#pragma unroll
    for (int jj = 0; jj < 16; jj++) {
      int idx = jj * 256 + tid;   // coalesced
      kv_s[(idx >> 6) * 65 + (idx & 63)] = kvsum[h * 4096 + idx];
      w_s[(idx >> 6) * 65 + (idx & 63)] = wgt[idx];
    }
    __syncthreads();
    int d = tid >> 2, e0 = (tid & 3) * 16;
    float acc[16];
#pragma unroll
    for (int e = 0; e < 16; e++) acc[e] = 0.f;
    for (int j = 0; j < 64; j++) {
      float kvj = kv_s[d * 65 + j];
#pragma unroll
      for (int e = 0; e < 16; e++)
        acc[e] = fmaf(kvj, w_s[(e0 + e) * 65 + j], acc[e]);
    }
    char* base = (char*)m2t + (size_t)h * 8192;
#pragma unroll
    for (int e = 0; e < 16; e++) {
      int ee = e0 + e;
      *(u16*)(base + ee * 128 + (((d >> 3) ^ (ee & 7)) * 16) + (d & 7) * 2) = f2bf_rne(acc[e]);
    }
  }
}

// ---------------- K_C: fused block-sparse + linear attention ----------------
// grid (64 m, 16 h), 256 thr = 4 waves; wave w owns Q rows [w*16, w*16+16).
// Single K/V LDS buffer + register prefetch (2 barriers/iter); m2 staged into
// the buffer AFTER the K-loop -> 33.3 KB LDS -> 4 blocks/CU (16 waves).
__global__ __launch_bounds__(256, 4) void fused_attn_kernel(const float* __restrict__ q,
                                                            const u16* __restrict__ kT,
                                                            const u16* __restrict__ vT,
                                                            const int* __restrict__ lut,
                                                            const u16* __restrict__ m2t,
                                                            const float* __restrict__ ksum,
                                                            const float* __restrict__ bproj,
                                                            float* __restrict__ out) {
  __shared__ __align__(16) char smem[33280];
  // [0,8K) Q | [8K,24K) buf: K 8K + V^T 8K (m2 after loop) | [24K,32K) P | ks | bias
  int m = blockIdx.x, h = blockIdx.y;
  int tid = threadIdx.x, w = tid >> 6, lane = tid & 63;
  int lq = lane & 15, quad = lane >> 4;
  u16* q_l = (u16*)smem;
  char* buf = smem + 8192;
  char* p_b = smem + 24576 + w * 2048;
  float* ks_s = (float*)(smem + 32768);
  float* b_s = (float*)(smem + 33024);

  const int lb = (h * NBLK + m) * TSEL;
  int blks[8];
#pragma unroll
  for (int t = 0; t < 8; t++) blks[t] = lut[lb + t];

  { // stage Q (bf16 swizzled)
#pragma unroll
    for (int c = 0; c < 2; c++) {
      int lo = c * 4096 + tid * 16;
      int r = lo >> 7;
      int j = ((lo >> 4) & 7) ^ (r & 7);
      const float* gp = q + ((size_t)(m * 64 + r)) * 1024 + h * 64 + j * 8;
      float4 a = *(const float4*)gp;
      float4 b = *(const float4*)(gp + 4);
      *(uint4*)(smem + lo) = make_uint4(pk2(a.x, a.y), pk2(a.z, a.w),
                                        pk2(b.x, b.y), pk2(b.z, b.w));
    }
  }
  { // stage K/V block 0 + ks + bias
    const uint4* kt0 = (const uint4*)(kT + ((size_t)(h * 64 + blks[0])) * 4096);
    const uint4* vt0 = (const uint4*)(vT + ((size_t)(h * 64 + blks[0])) * 4096);
    ((uint4*)buf)[tid] = kt0[tid];
    ((uint4*)buf)[256 + tid] = kt0[256 + tid];
    ((uint4*)(buf + 8192))[tid] = vt0[tid];
    ((uint4*)(buf + 8192))[256 + tid] = vt0[256 + tid];
    if (tid < 64) { ks_s[tid] = ksum[h * 64 + tid]; b_s[tid] = bproj[tid]; }
  }
  __syncthreads();

  const int qrow = w * 16 + lq;
  short8 qf[2];
#pragma unroll
  for (int ks = 0; ks < 2; ks++) qf[ks] = frag_row(q_l, qrow, 4 * ks + quad);

  float mrun = -INFINITY, lrun = 0.f;
  f4 o[4];
  f4 zz = {0.f, 0.f, 0.f, 0.f};
#pragma unroll
  for (int et = 0; et < 4; et++) o[et] = zz;

  const u16* kc = (const u16*)buf;
  const u16* vc = (const u16*)(buf + 8192);

  for (int t = 0; t < 8; t++) {
    // issue next-tile prefetch (16 transient VGPRs)
    uint4 pk0, pk1, pv0, pv1;
    if (t < 7) {
      const uint4* ktn = (const uint4*)(kT + ((size_t)(h * 64 + blks[t + 1])) * 4096);
      const uint4* vtn = (const uint4*)(vT + ((size_t)(h * 64 + blks[t + 1])) * 4096);
      pk0 = ktn[tid]; pk1 = ktn[256 + tid];
      pv0 = vtn[tid]; pv1 = vtn[256 + tid];
    }

    // S^T = K·Q^T
    f4 s[4];
#pragma unroll
    for (int kt = 0; kt < 4; kt++) s[kt] = zz;
#pragma unroll
    for (int ks = 0; ks < 2; ks++)
#pragma unroll
      for (int kt = 0; kt < 4; kt++)
        s[kt] = MFMA_BF16(frag_row(kc, kt * 16 + lq, 4 * ks + quad), qf[ks], s[kt]);

    // online softmax (16 scores/lane), P row lq -> wave-private slab
    float mp = -INFINITY;
#pragma unroll
    for (int kt = 0; kt < 4; kt++)
#pragma unroll
      for (int r = 0; r < 4; r++) mp = fmaxf(mp, s[kt][r]);
    mp = fmaxf(mp, __shfl_xor(mp, 16));
    mp = fmaxf(mp, __shfl_xor(mp, 32));
    mp *= 0.125f;
    float mn = fmaxf(mrun, mp);
    float al = __expf(mrun - mn);
    mrun = mn;
    float rs_ = 0.f;
#pragma unroll
    for (int kt = 0; kt < 4; kt++) {
      float p0 = __expf(fmaf(s[kt][0], 0.125f, -mn));
      float p1 = __expf(fmaf(s[kt][1], 0.125f, -mn));
      float p2 = __expf(fmaf(s[kt][2], 0.125f, -mn));
      float p3 = __expf(fmaf(s[kt][3], 0.125f, -mn));
      rs_ += p0 + p1 + p2 + p3;
      u32 lo32 = (__float_as_uint(p0) >> 16) | (__float_as_uint(p1) & 0xffff0000u);
      u32 hi32 = (__float_as_uint(p2) >> 16) | (__float_as_uint(p3) & 0xffff0000u);
      int addr = lq * 128 + (((kt * 2 + (quad >> 1)) ^ (lq & 7)) * 16) + (quad & 1) * 8;
      *(uint2*)(p_b + addr) = make_uint2(lo32, hi32);
    }
    rs_ += __shfl_xor(rs_, 16);
    rs_ += __shfl_xor(rs_, 32);
    lrun = lrun * al + rs_;
#pragma unroll
    for (int et = 0; et < 4; et++)
#pragma unroll
      for (int r = 0; r < 4; r++) o[et][r] *= al;

    // O^T += V^T · P^T
#pragma unroll
    for (int ks = 0; ks < 2; ks++) {
      short8 pf = frag_row((const u16*)p_b, lq, 4 * ks + quad);
#pragma unroll
      for (int et = 0; et < 4; et++)
        o[et] = MFMA_BF16(frag_row(vc, et * 16 + lq, 4 * ks + quad), pf, o[et]);
    }

    // rotate buffer: wait for all readers, drain prefetch, publish
    if (t < 7) {
      __syncthreads();
      ((uint4*)buf)[tid] = pk0;
      ((uint4*)buf)[256 + tid] = pk1;
      ((uint4*)(buf + 8192))[tid] = pv0;
      ((uint4*)(buf + 8192))[256 + tid] = pv1;
      __syncthreads();
    }
  }

  // ---- stage m2 into buf (reuse), then fused linear attention ----
  __syncthreads();
  {
    const uint4* src = (const uint4*)((const char*)m2t + (size_t)h * 8192);
    ((uint4*)buf)[tid] = src[tid];
    ((uint4*)buf)[256 + tid] = src[256 + tid];
  }
  __syncthreads();
  u16* m2_l = (u16*)buf;

  short8 qa = frag_row(q_l, qrow, 2 * quad);
  short8 qb = frag_row(q_l, qrow, 2 * quad + 1);
  float ev[16];
  float mx = -INFINITY;
#pragma unroll
  for (int j = 0; j < 8; j++) { float x = bf2f((u16)qa[j]); ev[j] = x; mx = fmaxf(mx, x); }
#pragma unroll
  for (int j = 0; j < 8; j++) { float x = bf2f((u16)qb[j]); ev[8 + j] = x; mx = fmaxf(mx, x); }
  mx = fmaxf(mx, __shfl_xor(mx, 16));
  mx = fmaxf(mx, __shfl_xor(mx, 32));
  float sum = 0.f, eks = 0.f;
#pragma unroll
  for (int j = 0; j < 16; j++) {
    float e = __expf(ev[j] - mx);
    ev[j] = e;
    sum += e;
    eks += e * ks_s[quad * 16 + j];
  }
  sum += __shfl_xor(sum, 16); sum += __shfl_xor(sum, 32);
  eks += __shfl_xor(eks, 16); eks += __shfl_xor(eks, 32);
  float invs = 1.0f / sum;
  float den = fmaf(eks, invs, 1e-6f);
  float scale = invs / den;
  // E row lq -> wave slab (blocks 2*quad, 2*quad+1)
  uint4 e0v = make_uint4(pk2(ev[0], ev[1]), pk2(ev[2], ev[3]),
                         pk2(ev[4], ev[5]), pk2(ev[6], ev[7]));
  uint4 e1v = make_uint4(pk2(ev[8], ev[9]), pk2(ev[10], ev[11]),
                         pk2(ev[12], ev[13]), pk2(ev[14], ev[15]));
  *(uint4*)(p_b + lq * 128 + (((2 * quad) ^ (lq & 7)) * 16)) = e0v;
  *(uint4*)(p_b + lq * 128 + (((2 * quad + 1) ^ (lq & 7)) * 16)) = e1v;

  f4 oc[4];
#pragma unroll
  for (int et = 0; et < 4; et++) oc[et] = zz;
#pragma unroll
  for (int ks2 = 0; ks2 < 2; ks2++) {
    short8 ef = frag_row((const u16*)p_b, lq, 4 * ks2 + quad);
#pragma unroll
    for (int et = 0; et < 4; et++)
      oc[et] = MFMA_BF16(frag_row(m2_l, et * 16 + lq, 4 * ks2 + quad), ef, oc[et]);
  }

  // ---- single write: out = o_s/l + o_l*scale + bias ----
  float invl = 1.0f / lrun;
  float* gp = out + ((size_t)(m * 64 + qrow)) * 1024 + h * 64 + quad * 4;
#pragma unroll
  for (int et = 0; et < 4; et++) {
    int e0 = et * 16 + quad * 4;
    float4 ov;
    ov.x = o[et][0] * invl + oc[et][0] * scale + b_s[e0 + 0];
    ov.y = o[et][1] * invl + oc[et][1] * scale + b_s[e0 + 1];
    ov.z = o[et][2] * invl + oc[et][2] * scale + b_s[e0 + 2];
    ov.w = o[et][3] * invl + oc[et][3] * scale + b_s[e0 + 3];
    *(float4*)(gp + et * 16) = ov;
  }
}

extern "C" void kernel_launch(void* const* d_in, const int* in_sizes, int n_in,
                              void* d_out, int out_size, void* d_ws, size_t ws_size,
                              hipStream_t stream) {
  const float* q = (const float*)d_in[0];
  const float* k = (const float*)d_in[1];
  const float* v = (const float*)d_in[2];
  const float* w = (const float*)d_in[3];
  const float* b = (const float*)d_in[4];
  float* out = (float*)d_out;

  // ws: kT 8MB u16 | vT 8MB u16 | qkp 1MB f32 | kmv 256KB f32 | lut 32KB |
  //     kvsum 256KB f32 | ksum 4KB f32 | m2t 128KB u16
  u16* kT = (u16*)d_ws;
  u16* vT = kT + 4194304;
  float* qkp = (float*)(vT + 4194304);
  float* kmv = qkp + 262144;
  int* lut = (int*)(kmv + 65536);
  float* kvsum = (float*)(lut + 8192);
  float* ksum = kvsum + 65536;
  u16* m2t = (u16*)(ksum + 1024);

  hipMemsetAsync(kvsum, 0, (65536 + 1024) * sizeof(float), stream);
  prep_kernel<<<dim3(64, 16), 256, 0, stream>>>(q, k, v, kT, vT, kvsum, ksum, kmv, qkp);
  post_kernel<<<272, 256, 0, stream>>>(qkp, kmv, kvsum, w, lut, m2t);
  fused_attn_kernel<<<dim3(64, 16), 256, 0, stream>>>(q, kT, vT, lut, m2t, ksum, b, out);
}